// Round 15
// baseline (24.081 us; speedup 1.0000x reference)
//
#include <hip/hip_runtime.h>

// QuadraticWeightedKappa: N=4194304 rows x 5 classes (f32 logits), int32
// targets. Output: one f32 scalar -kappa.
//
// Correctness model (locked in R5, absmax=0.0): counts = first-max-wins raw
// argmax; finalize = f32 XLA-CPU pipeline with SEQUENTIAL l2r 25-elem sums.
//
// Perf history:
//  R5/R8 ~56-59us: 25 atomics x 4096 blocks on 2 lines = L2 RMW serial floor.
//  R6 210us: per-block __threadfence => cross-XCD invalidate storm.
//  R9/R10/R11 ~28.5: replica atomics; load pattern & intra-block sync flat.
//  R12 71us: fused finalize + launch_bounds(256,8) -> hot-path scratch spill.
//  R13 40.7us: single-block finalize over a 512KB slot table (latency-bound).
//  R14 23.0us BEST: 512 blocks x 8 tiles, per-block stores, 64KB table.
//    Residual vs ~15us streaming floor: only 2 waves/SIMD, serial tile
//    chain/wave -> load-return latency under-hidden.
//  R15: TLP bump only. 1024 blocks x 4 tiles (4 waves/SIMD, 16 waves/CU),
//    hist body unchanged. Slot table 128KB; finalize widened to 1024 thr
//    (8 independent uint4 loads each) to keep the reduce ~2us.
//
// ws layout: [1024][32] uint = 128 KB, fully overwritten every launch.

#define KCLS 5
#define HBLK 1024         // hist blocks
#define TILES 4           // grid-stride tiles per block

__global__ __launch_bounds__(256) void kappa_hist(const float* __restrict__ x,
                                                  const int* __restrict__ tgt,
                                                  unsigned int* __restrict__ ws) {
    __shared__ unsigned int h[128];   // 4 waves x 32-slot histograms
    const int tid = threadIdx.x;
    const int lane = tid & 63;
    unsigned int* hw = h + ((tid >> 6) << 5);
    if (lane < 32) hw[lane] = 0u;     // wave-local init; per-wave LDS FIFO

    const float4* xv = (const float4*)x;
#pragma unroll 1
    for (int s = 0; s < TILES; ++s) {
        const int t = (s * HBLK + blockIdx.x) * 256 + tid;   // 4 rows/thread
        float f[20];
#pragma unroll
        for (int k = 0; k < 5; ++k) {
            float4 v = xv[t * 5 + k]; // 80B lane stride
            f[4 * k + 0] = v.x;
            f[4 * k + 1] = v.y;
            f[4 * k + 2] = v.z;
            f[4 * k + 3] = v.w;
        }
        const int4 tg = ((const int4*)tgt)[t];  // coalesced
        const int tgv[4] = {tg.x, tg.y, tg.z, tg.w};
#pragma unroll
        for (int r = 0; r < 4; ++r) {
            const float* fr = f + 5 * r;
            float m = fr[0];
            int k = 0;
#pragma unroll
            for (int j = 1; j < KCLS; ++j)
                if (fr[j] > m) { m = fr[j]; k = j; }   // first-max-wins
            atomicAdd(&hw[tgv[r] * KCLS + k], 1u);
        }
    }
    __syncthreads();                  // merge waves (the only barrier)

    // per-block result slot: plain coalesced stores, fully overwritten
    // every launch (slots 25..31 = 0) -> no memset, no atomics anywhere.
    if (tid < 32) {
        unsigned int s = 0;
        if (tid < KCLS * KCLS)
            s = h[tid] + h[32 + tid] + h[64 + tid] + h[96 + tid];
        ws[blockIdx.x * 32 + tid] = s;
    }
}

// XLA CPU full-reduce: init 0.0f, sequential left-to-right adds.
__device__ __forceinline__ float seq25(const float* a) {
    float res = 0.0f;
#pragma unroll
    for (int i = 0; i < 25; ++i) res = __fadd_rn(res, a[i]);
    return res;
}

__global__ __launch_bounds__(1024) void kappa_finalize(const unsigned int* __restrict__ ws,
                                                       float* __restrict__ out,
                                                       int n) {
    __shared__ unsigned int lp[1024][4];  // per-thread uint4 partials (16 KB)
    __shared__ unsigned int cnt[25];
    const int tid = threadIdx.x;

    // [1024][32] uint = 8192 uint4. thread t: chunk c=t&7 (bins 4c..4c+3),
    // rows r = t>>3 + 128k, k=0..7. k=0 covers flat idx 0..1023: coalesced.
    const uint4* w4 = (const uint4*)ws;
    const int c = tid & 7, r0 = tid >> 3;
    uint4 acc = make_uint4(0u, 0u, 0u, 0u);
#pragma unroll
    for (int k = 0; k < HBLK / 128; ++k) {
        uint4 v = w4[(r0 + 128 * k) * 8 + c];   // independent loads
        acc.x += v.x; acc.y += v.y; acc.z += v.z; acc.w += v.w;
    }
    lp[tid][0] = acc.x; lp[tid][1] = acc.y; lp[tid][2] = acc.z; lp[tid][3] = acc.w;
    __syncthreads();

    if (tid < KCLS * KCLS) {
        const int cc = tid >> 2, comp = tid & 3;   // chunk, component
        unsigned int s = 0;
        for (int g = 0; g < 128; ++g) s += lp[g * 8 + cc][comp];
        cnt[tid] = s;
    }
    __syncthreads();
    if (tid != 0) return;

    // ---- locked bit-exact f32 pipeline (XLA-CPU semantics) ----
    const float fn = (float)n;  // 2^22, exact
    float conf[25];
#pragma unroll
    for (int k = 0; k < 25; ++k)
        conf[k] = __fdiv_rn((float)cnt[k], fn);  // exact

    float w[25];
#pragma unroll
    for (int i = 0; i < KCLS; ++i)
#pragma unroll
        for (int j = 0; j < KCLS; ++j)
            w[i * KCLS + j] = (float)((i - j) * (i - j)) / 16.0f;  // exact

    float mt[KCLS], mp[KCLS];
#pragma unroll
    for (int i = 0; i < KCLS; ++i) {
        float s = 0.0f;
#pragma unroll
        for (int j = 0; j < KCLS; ++j) s = __fadd_rn(s, conf[i * KCLS + j]);
        mt[i] = s;  // exact: multiples of 2^-22
    }
#pragma unroll
    for (int j = 0; j < KCLS; ++j) {
        float s = 0.0f;
#pragma unroll
        for (int i = 0; i < KCLS; ++i) s = __fadd_rn(s, conf[i * KCLS + j]);
        mp[j] = s;
    }

    float a[25], b[25];
#pragma unroll
    for (int k = 0; k < 25; ++k) {
        a[k] = __fmul_rn(conf[k], w[k]);                 // RN mul (no FMA)
        float e = __fmul_rn(mt[k / KCLS], mp[k % KCLS]); // outer, RN
        b[k] = __fmul_rn(e, w[k]);                       // RN mul
    }

    float num = seq25(a);
    float den = seq25(b);
    float den2 = __fadd_rn(den, 1e-7f);   // weak scalar -> f32
    float q = __fdiv_rn(num, den2);
    float kappa = __fsub_rn(1.0f, q);
    out[0] = -kappa;
}

extern "C" void kernel_launch(void* const* d_in, const int* in_sizes, int n_in,
                              void* d_out, int out_size, void* d_ws, size_t ws_size,
                              hipStream_t stream) {
    const float* x = (const float*)d_in[0];
    const int* tgt = (const int*)d_in[1];
    float* out = (float*)d_out;
    unsigned int* ws = (unsigned int*)d_ws;

    const int n = in_sizes[1];          // rows (4194304 = 2^22)
    // HBLK * TILES * 1024 rows == n (1024 * 4 * 1024 = 2^22), exact

    kappa_hist<<<HBLK, 256, 0, stream>>>(x, tgt, ws);
    kappa_finalize<<<1, 1024, 0, stream>>>(ws, out, n);
}

// Round 18
// 23.519 us; speedup vs baseline: 1.0239x; 1.0239x over previous
//
#include <hip/hip_runtime.h>

// QuadraticWeightedKappa: N=4194304 rows x 5 classes (f32 logits), int32
// targets. Output: one f32 scalar -kappa.
//
// Correctness model (locked in R5, absmax=0.0): counts = first-max-wins raw
// argmax; finalize = f32 XLA-CPU pipeline with SEQUENTIAL l2r 25-elem sums.
//
// Perf history:
//  R5/R8 ~56-59us: shared-line atomic RMW floor -> replica/store merges.
//  R6 210us: per-block __threadfence storm. R12 71us: spill via fused
//  finalize + launch_bounds cap. R13 40.7us: fat single-block reduce.
//  R9/R10/R11 ~28.5: coalesced-vs-divergent & barriers all FLAT -> TA
//    divergence falsified. R15 (2x TLP): flat -> TLP falsified.
//  R14 23.0us BEST: 512 blocks x 8 tiles, direct divergent loads,
//    atomic-free store-slot merge, small 2-dispatch finalize.
//  R16/R17 WRONG: LDS wave-staging pipeline miscounted rows (2 strikes);
//    structure abandoned -- its motivating theory was already falsified.
//  R18: R14 body + REGISTER double-buffer prefetch (ILP, not TLP): issue
//    tile s+1's 6 loads before computing tile s. No LDS, no row remapping
//    (mapping bit-identical to R14). Tests the last live theory: per-wave
//    load->drain->compute serialization with 2 waves/SIMD.
//
// ws layout: [512][32] uint = 64 KB, fully overwritten every launch.

#define KCLS 5
#define HBLK 512          // hist blocks
#define TILES 8           // tiles per block, 1024 rows each

__global__ __launch_bounds__(256) void kappa_hist(const float* __restrict__ x,
                                                  const int* __restrict__ tgt,
                                                  unsigned int* __restrict__ ws) {
    __shared__ unsigned int h[128];   // 4 waves x 32-slot histograms
    const int tid = threadIdx.x;
    const int lane = tid & 63;
    unsigned int* hw = h + ((tid >> 6) << 5);
    if (lane < 32) hw[lane] = 0u;     // wave-local init; per-wave LDS FIFO

    const float4* xv = (const float4*)x;
    const int4* tv = (const int4*)tgt;

    float4 fb[2][5];                  // register double buffer (static
    int4 tb[2];                       //  indices after full unroll)

    // prologue: issue tile 0 loads
    {
        const int t0 = (0 * HBLK + blockIdx.x) * 256 + tid;  // 4-row unit
#pragma unroll
        for (int k = 0; k < 5; ++k) fb[0][k] = xv[t0 * 5 + k];
        tb[0] = tv[t0];
    }

#pragma unroll
    for (int s = 0; s < TILES; ++s) {
        // prefetch tile s+1 first: its loads stay in flight while tile s
        // computes (compiler waits vmcnt only for tile-s's older loads)
        if (s + 1 < TILES) {
            const int t1 = ((s + 1) * HBLK + blockIdx.x) * 256 + tid;
#pragma unroll
            for (int k = 0; k < 5; ++k) fb[(s + 1) & 1][k] = xv[t1 * 5 + k];
            tb[(s + 1) & 1] = tv[t1];
        }

        // compute tile s: same row<->target mapping as R14 (4 consecutive
        // rows per thread; int4 target for the same 4 rows)
        float f[20];
#pragma unroll
        for (int k = 0; k < 5; ++k) {
            f[4 * k + 0] = fb[s & 1][k].x;
            f[4 * k + 1] = fb[s & 1][k].y;
            f[4 * k + 2] = fb[s & 1][k].z;
            f[4 * k + 3] = fb[s & 1][k].w;
        }
        const int4 tg = tb[s & 1];
        const int tgv[4] = {tg.x, tg.y, tg.z, tg.w};
#pragma unroll
        for (int r = 0; r < 4; ++r) {
            const float* fr = f + 5 * r;
            float m = fr[0];
            int k = 0;
#pragma unroll
            for (int j = 1; j < KCLS; ++j)
                if (fr[j] > m) { m = fr[j]; k = j; }   // first-max-wins
            atomicAdd(&hw[tgv[r] * KCLS + k], 1u);
        }
    }
    __syncthreads();                  // merge waves (the only barrier)

    // per-block result slot: plain coalesced stores, fully overwritten
    // every launch (slots 25..31 = 0) -> no memset, no atomics anywhere.
    if (tid < 32) {
        unsigned int s = 0;
        if (tid < KCLS * KCLS)
            s = h[tid] + h[32 + tid] + h[64 + tid] + h[96 + tid];
        ws[blockIdx.x * 32 + tid] = s;
    }
}

// XLA CPU full-reduce: init 0.0f, sequential left-to-right adds.
__device__ __forceinline__ float seq25(const float* a) {
    float res = 0.0f;
#pragma unroll
    for (int i = 0; i < 25; ++i) res = __fadd_rn(res, a[i]);
    return res;
}

__global__ __launch_bounds__(256) void kappa_finalize(const unsigned int* __restrict__ ws,
                                                      float* __restrict__ out,
                                                      int n) {
    __shared__ unsigned int lp[256][4];   // per-thread uint4 partials
    __shared__ unsigned int cnt[25];
    const int tid = threadIdx.x;

    // [512][32] uint = 4096 uint4. thread t: chunk c=t&7 (bins 4c..4c+3),
    // rows r = t>>3 + 32k. k=0 covers flat idx 0..255: coalesced.
    const uint4* w4 = (const uint4*)ws;
    const int c = tid & 7, r0 = tid >> 3;
    uint4 acc = make_uint4(0u, 0u, 0u, 0u);
#pragma unroll
    for (int k = 0; k < HBLK / 32; ++k) {
        uint4 v = w4[(r0 + 32 * k) * 8 + c];
        acc.x += v.x; acc.y += v.y; acc.z += v.z; acc.w += v.w;
    }
    lp[tid][0] = acc.x; lp[tid][1] = acc.y; lp[tid][2] = acc.z; lp[tid][3] = acc.w;
    __syncthreads();

    if (tid < KCLS * KCLS) {
        const int cc = tid >> 2, comp = tid & 3;   // chunk, component
        unsigned int s = 0;
#pragma unroll
        for (int g = 0; g < 32; ++g) s += lp[g * 8 + cc][comp];
        cnt[tid] = s;
    }
    __syncthreads();
    if (tid != 0) return;

    // ---- locked bit-exact f32 pipeline (XLA-CPU semantics) ----
    const float fn = (float)n;  // 2^22, exact
    float conf[25];
#pragma unroll
    for (int k = 0; k < 25; ++k)
        conf[k] = __fdiv_rn((float)cnt[k], fn);  // exact

    float w[25];
#pragma unroll
    for (int i = 0; i < KCLS; ++i)
#pragma unroll
        for (int j = 0; j < KCLS; ++j)
            w[i * KCLS + j] = (float)((i - j) * (i - j)) / 16.0f;  // exact

    float mt[KCLS], mp[KCLS];
#pragma unroll
    for (int i = 0; i < KCLS; ++i) {
        float s = 0.0f;
#pragma unroll
        for (int j = 0; j < KCLS; ++j) s = __fadd_rn(s, conf[i * KCLS + j]);
        mt[i] = s;  // exact: multiples of 2^-22
    }
#pragma unroll
    for (int j = 0; j < KCLS; ++j) {
        float s = 0.0f;
#pragma unroll
        for (int i = 0; i < KCLS; ++i) s = __fadd_rn(s, conf[i * KCLS + j]);
        mp[j] = s;
    }

    float a[25], b[25];
#pragma unroll
    for (int k = 0; k < 25; ++k) {
        a[k] = __fmul_rn(conf[k], w[k]);                 // RN mul (no FMA)
        float e = __fmul_rn(mt[k / KCLS], mp[k % KCLS]); // outer, RN
        b[k] = __fmul_rn(e, w[k]);                       // RN mul
    }

    float num = seq25(a);
    float den = seq25(b);
    float den2 = __fadd_rn(den, 1e-7f);   // weak scalar -> f32
    float q = __fdiv_rn(num, den2);
    float kappa = __fsub_rn(1.0f, q);
    out[0] = -kappa;
}

extern "C" void kernel_launch(void* const* d_in, const int* in_sizes, int n_in,
                              void* d_out, int out_size, void* d_ws, size_t ws_size,
                              hipStream_t stream) {
    const float* x = (const float*)d_in[0];
    const int* tgt = (const int*)d_in[1];
    float* out = (float*)d_out;
    unsigned int* ws = (unsigned int*)d_ws;

    const int n = in_sizes[1];          // rows (4194304 = 2^22)
    // HBLK * TILES * 1024 rows == n (512 * 8 * 1024 = 2^22), exact

    kappa_hist<<<HBLK, 256, 0, stream>>>(x, tgt, ws);
    kappa_finalize<<<1, 256, 0, stream>>>(ws, out, n);
}